// Round 5
// baseline (655.850 us; speedup 1.0000x reference)
//
#include <hip/hip_runtime.h>
#include <math.h>

#define TOK  1024
#define HID  1024
#define NEXP 16

typedef __attribute__((ext_vector_type(8))) short bf16x8;
typedef __attribute__((ext_vector_type(4))) float f32x4;

__device__ __forceinline__ unsigned pack2(float f0, float f1) {
    union { float f; unsigned u; } a, b; a.f = f0; b.f = f1;
    return __builtin_amdgcn_perm(b.u + 0x8000u, a.u + 0x8000u, 0x07060302u);
}
__device__ __forceinline__ unsigned short f2bf(float f) {
    union { float f; unsigned u; } v; v.f = f;
    return (unsigned short)((v.u + 0x8000u) >> 16);
}

// ---------------- init: zero counts + zero final-out region ----------------
__global__ void k_init(float* __restrict__ out, int* __restrict__ counts) {
    size_t i = (size_t)blockIdx.x * blockDim.x + threadIdx.x;   // 262144 float4
    ((float4*)out)[i] = make_float4(0.f, 0.f, 0.f, 0.f);
    if (blockIdx.x == 0 && threadIdx.x < 32) counts[threadIdx.x] = 0;
}

// ---------------- router: 1 wave per token (fp32 exact) + Xbf emission -----
__global__ __launch_bounds__(64)
void k_router(const float* __restrict__ x, const int* __restrict__ tt,
              const float* __restrict__ rw_t, const float* __restrict__ b_t,
              const float* __restrict__ rw_v, const float* __restrict__ b_v,
              float* __restrict__ out_logits,
              int* __restrict__ counts, int* __restrict__ lists,
              float* __restrict__ wlist, unsigned short* __restrict__ Xbf)
{
    const int t = blockIdx.x;
    const int lane = threadIdx.x;
    const bool vis = (tt[t] != 0);
    const float* rw   = vis ? rw_v : rw_t;
    const float* bias = vis ? b_v  : b_t;
    const float* xr = x + (size_t)t * HID;

    // bf16 copy of this token's row (k-contiguous for MFMA A-frags)
#pragma unroll
    for (int jj = 0; jj < 2; ++jj) {
        int j0 = jj * 512 + lane * 8;
        float4 lo = *(const float4*)(xr + j0);
        float4 hi = *(const float4*)(xr + j0 + 4);
        union { bf16x8 v; unsigned d[4]; } u;
        u.d[0] = pack2(lo.x, lo.y); u.d[1] = pack2(lo.z, lo.w);
        u.d[2] = pack2(hi.x, hi.y); u.d[3] = pack2(hi.z, hi.w);
        *(bf16x8*)(Xbf + (size_t)t * HID + j0) = u.v;
    }

    float acc[NEXP];
#pragma unroll
    for (int e = 0; e < NEXP; ++e) acc[e] = 0.f;
    for (int j = 0; j < HID; j += 64) {
        const float xv = xr[j + lane];
#pragma unroll
        for (int e = 0; e < NEXP; ++e)
            acc[e] = fmaf(xv, rw[(size_t)e * HID + j + lane], acc[e]);
    }
#pragma unroll
    for (int e = 0; e < NEXP; ++e) {
        float v = acc[e];
#pragma unroll
        for (int off = 32; off; off >>= 1) v += __shfl_xor(v, off);
        acc[e] = v;
    }
    if (lane < NEXP) out_logits[(size_t)t * NEXP + lane] = acc[lane];

    if (lane == 0) {
        float mx = acc[0];
#pragma unroll
        for (int e = 1; e < NEXP; ++e) mx = fmaxf(mx, acc[e]);
        float p[NEXP], s = 0.f;
#pragma unroll
        for (int e = 0; e < NEXP; ++e) { p[e] = expf(acc[e] - mx); s += p[e]; }
        const float inv = 1.f / s;
#pragma unroll
        for (int e = 0; e < NEXP; ++e) p[e] *= inv;

        int s1 = 0; float v1 = p[0] + bias[0];
#pragma unroll
        for (int e = 1; e < NEXP; ++e) {
            float c = p[e] + bias[e];
            if (c > v1) { v1 = c; s1 = e; }
        }
        int s2 = -1; float v2 = -1e30f;
#pragma unroll
        for (int e = 0; e < NEXP; ++e) {
            if (e == s1) continue;
            float c = p[e] + bias[e];
            if (c > v2) { v2 = c; s2 = e; }
        }
        float w1 = p[s1], w2 = p[s2];
        float sw = fmaxf(w1 + w2, 1e-12f);
        w1 /= sw; w2 /= sw;

        const int base = vis ? NEXP : 0;
        int pos1 = atomicAdd(&counts[base + s1], 1);
        lists[(base + s1) * TOK + pos1] = t * 2 + 0;
        wlist[(base + s1) * TOK + pos1] = w1;
        int pos2 = atomicAdd(&counts[base + s2], 1);
        lists[(base + s2) * TOK + pos2] = t * 2 + 1;
        wlist[(base + s2) * TOK + pos2] = w2;
    }
}

// ---------------- gate+up fused GEMM + silu (routed z<32, shared z==32) ----
// Block: 64 tokens x 64 i-cols (gate+up pair). Weight chunks 64k x 128c fp32
// staged global->VGPR->LDS (software-pipelined), XOR-swizzled (2-way banks).
// launch_bounds(256,2): unified VGPR+AGPR cap 256/wave -> no scratch spill
// (r4's (256,4) capped at ~128 and spilled the R[8] pipeline regs: 156 MB
// of scratch WRITE_SIZE).
__global__ __launch_bounds__(256, 2)
void k_gu(const unsigned short* __restrict__ Xbf,
          const float* __restrict__ gut, const float* __restrict__ guv,
          const float* __restrict__ sg, const float* __restrict__ su,
          const int* __restrict__ counts, const int* __restrict__ lists,
          unsigned short* __restrict__ hbuf, unsigned short* __restrict__ hsh)
{
    const int z = blockIdx.z;
    int M, I, str;
    const float *Wg, *Wu;
    if (z == 32) { M = TOK; I = 1024; str = 1024; Wg = sg; Wu = su; }
    else {
        M = counts[z];
        const int mod = z >> 4, e = z & 15;
        I = mod ? 256 : 512; str = 2 * I;
        const float* base = mod ? (guv + (size_t)e * HID * 512)
                                : (gut + (size_t)e * HID * 1024);
        Wg = base; Wu = base + I;
    }
    const int xI = blockIdx.x * 64;
    const int m0 = blockIdx.y * 64;
    if (xI >= I || m0 >= M) return;

    __shared__ float bs[8192];                  // 32 KB, single buffer
    __shared__ int s_aid[64];

    const int tid = threadIdx.x;
    const int wid = tid >> 6, lane = tid & 63;
    const int lm = lane & 15, q = lane >> 4;

    if (tid < 64) {
        int r = m0 + tid;
        s_aid[tid] = (z == 32) ? r : ((r < M) ? lists[z * TOK + r] : -1);
    }
    __syncthreads();

    const unsigned short* arow[4];
#pragma unroll
    for (int s = 0; s < 4; ++s) {
        int aid = s_aid[s * 16 + lm];
        int tr = (z == 32) ? aid : (aid < 0 ? 0 : (aid >> 1));
        arow[s] = Xbf + (size_t)tr * HID;
    }

    // staging map: u = r*256+tid -> (k row, 16B cell), swizzle by (k>>3)&1
    int urow[8], uc4[8], scell[8];
#pragma unroll
    for (int r = 0; r < 8; ++r) {
        int u = r * 256 + tid;
        int k = u >> 5;
        urow[r] = k; uc4[r] = u & 31;
        scell[r] = k * 32 + ((u & 31) ^ (((k >> 3) & 1) << 2));
    }
    // fragment read base (float idx at k=q*8; parity (q&1) holds for ks=0,32)
    int fidx[2];
#pragma unroll
    for (int reg = 0; reg < 2; ++reg) {
        int c = reg * 64 + wid * 16 + lm;
        fidx[reg] = (q * 8) * 128 + (((c >> 2) ^ ((q & 1) << 2)) * 4 + (c & 3));
    }

    float4 R[8];
#pragma unroll
    for (int r = 0; r < 8; ++r) {
        int c4 = uc4[r];
        const float* gp = (c4 < 16) ? (Wg + (size_t)urow[r] * str + xI + c4 * 4)
                                    : (Wu + (size_t)urow[r] * str + xI + (c4 - 16) * 4);
        R[r] = *(const float4*)gp;
    }

    f32x4 accG[4] = {}, accU[4] = {};

    for (int kc = 0; kc < 16; ++kc) {
        if (kc) __syncthreads();                 // WAR: prev chunk reads done
#pragma unroll
        for (int r = 0; r < 8; ++r)
            *(float4*)&bs[scell[r] * 4] = R[r];
        __syncthreads();                         // chunk visible

        // A-frags for this chunk (issued BEFORE the next weight prefetch so
        // their vmcnt wait leaves the R loads in flight)
        bf16x8 af[2][4];
        const int kg = kc * 64 + q * 8;
#pragma unroll
        for (int s = 0; s < 4; ++s) {
            af[0][s] = *(const bf16x8*)(arow[s] + kg);
            af[1][s] = *(const bf16x8*)(arow[s] + kg + 32);
        }
        // prefetch next weight chunk into VGPRs (latency hidden by compute)
        if (kc + 1 < 16) {
            const int k0 = (kc + 1) * 64;
#pragma unroll
            for (int r = 0; r < 8; ++r) {
                int c4 = uc4[r];
                const float* gp = (c4 < 16) ? (Wg + (size_t)(k0 + urow[r]) * str + xI + c4 * 4)
                                            : (Wu + (size_t)(k0 + urow[r]) * str + xI + (c4 - 16) * 4);
                R[r] = *(const float4*)gp;
            }
        }
#pragma unroll
        for (int ks2 = 0; ks2 < 2; ++ks2) {
            const int ks = ks2 * 32;
            bf16x8 bg, bu;
            {
                float b[8];
#pragma unroll
                for (int j = 0; j < 8; ++j) b[j] = bs[fidx[0] + (ks + j) * 128];
                union { bf16x8 v; unsigned d[4]; } u;
                u.d[0] = pack2(b[0], b[1]); u.d[1] = pack2(b[2], b[3]);
                u.d[2] = pack2(b[4], b[5]); u.d[3] = pack2(b[6], b[7]);
                bg = u.v;
            }
            {
                float b[8];
#pragma unroll
                for (int j = 0; j < 8; ++j) b[j] = bs[fidx[1] + (ks + j) * 128];
                union { bf16x8 v; unsigned d[4]; } u;
                u.d[0] = pack2(b[0], b[1]); u.d[1] = pack2(b[2], b[3]);
                u.d[2] = pack2(b[4], b[5]); u.d[3] = pack2(b[6], b[7]);
                bu = u.v;
            }
#pragma unroll
            for (int s = 0; s < 4; ++s) {
                accG[s] = __builtin_amdgcn_mfma_f32_16x16x32_bf16(af[ks2][s], bg, accG[s], 0, 0, 0);
                accU[s] = __builtin_amdgcn_mfma_f32_16x16x32_bf16(af[ks2][s], bu, accU[s], 0, 0, 0);
            }
        }
    }

    const int i = xI + wid * 16 + lm;
#pragma unroll
    for (int s = 0; s < 4; ++s)
#pragma unroll
        for (int r = 0; r < 4; ++r) {
            int row = s * 16 + q * 4 + r;
            int aid = s_aid[row];
            if (aid < 0) continue;
            float g = accG[s][r], uu = accU[s][r];
            float h = g / (1.f + __expf(-g)) * uu;
            if (z == 32) hsh[(size_t)aid * 1024 + i] = f2bf(h);
            else         hbuf[(size_t)aid * 512 + i] = f2bf(h);
        }
}

// ---------------- down GEMM (routed z<32, shared z==32) --------------------
// A = h (bf16 k-contiguous, direct global/L2). Weights staged like k_gu.
__global__ __launch_bounds__(256, 2)
void k_down(const unsigned short* __restrict__ hbuf, const unsigned short* __restrict__ hsh,
            const float* __restrict__ dnt, const float* __restrict__ dnv,
            const float* __restrict__ sd,
            const int* __restrict__ counts, const int* __restrict__ lists,
            const float* __restrict__ wlist, float* __restrict__ out)
{
    const int z = blockIdx.z;
    int M, K;
    const float* W;
    if (z == 32) { M = TOK; K = 1024; W = sd; }
    else {
        M = counts[z];
        const int mod = z >> 4, e = z & 15;
        K = mod ? 256 : 512;
        W = mod ? (dnv + (size_t)e * 256 * 1024) : (dnt + (size_t)e * 512 * 1024);
    }
    const int n0 = blockIdx.x * 128;
    const int m0 = blockIdx.y * 64;
    if (m0 >= M) return;

    __shared__ float bs[8192];
    __shared__ int s_aid[64];
    __shared__ float s_w[64];

    const int tid = threadIdx.x;
    const int wid = tid >> 6, lane = tid & 63;
    const int lm = lane & 15, q = lane >> 4;

    if (tid < 64) {
        int r = m0 + tid;
        if (z == 32)    { s_aid[tid] = r; s_w[tid] = 1.f; }
        else if (r < M) { s_aid[tid] = lists[z * TOK + r]; s_w[tid] = wlist[z * TOK + r]; }
        else            { s_aid[tid] = -1; s_w[tid] = 0.f; }
    }
    __syncthreads();

    const unsigned short* hrow[4];
#pragma unroll
    for (int s = 0; s < 4; ++s) {
        int aid = s_aid[s * 16 + lm];
        hrow[s] = (z == 32) ? (hsh + (size_t)aid * 1024)
                            : (hbuf + (size_t)(aid < 0 ? 0 : aid) * 512);
    }

    int urow[8], uc4[8], scell[8];
#pragma unroll
    for (int r = 0; r < 8; ++r) {
        int u = r * 256 + tid;
        int k = u >> 5;
        urow[r] = k; uc4[r] = u & 31;
        scell[r] = k * 32 + ((u & 31) ^ (((k >> 3) & 1) << 2));
    }
    int fidx[2];
#pragma unroll
    for (int t = 0; t < 2; ++t) {
        int c = wid * 32 + t * 16 + lm;
        fidx[t] = (q * 8) * 128 + (((c >> 2) ^ ((q & 1) << 2)) * 4 + (c & 3));
    }

    float4 R[8];
#pragma unroll
    for (int r = 0; r < 8; ++r)
        R[r] = *(const float4*)(W + (size_t)urow[r] * 1024 + n0 + uc4[r] * 4);

    f32x4 acc[4][2] = {};
    const int NC = K >> 6;

    for (int kc = 0; kc < NC; ++kc) {
        if (kc) __syncthreads();
#pragma unroll
        for (int r = 0; r < 8; ++r)
            *(float4*)&bs[scell[r] * 4] = R[r];
        __syncthreads();

        bf16x8 af[2][4];
        const int kg = kc * 64 + q * 8;
#pragma unroll
        for (int s = 0; s < 4; ++s) {
            af[0][s] = *(const bf16x8*)(hrow[s] + kg);
            af[1][s] = *(const bf16x8*)(hrow[s] + kg + 32);
        }
        if (kc + 1 < NC) {
            const int k0 = (kc + 1) * 64;
#pragma unroll
            for (int r = 0; r < 8; ++r)
                R[r] = *(const float4*)(W + (size_t)(k0 + urow[r]) * 1024 + n0 + uc4[r] * 4);
        }
#pragma unroll
        for (int ks2 = 0; ks2 < 2; ++ks2) {
            const int ks = ks2 * 32;
            bf16x8 bt[2];
#pragma unroll
            for (int t = 0; t < 2; ++t) {
                float b[8];
#pragma unroll
                for (int j = 0; j < 8; ++j) b[j] = bs[fidx[t] + (ks + j) * 128];
                union { bf16x8 v; unsigned d[4]; } u;
                u.d[0] = pack2(b[0], b[1]); u.d[1] = pack2(b[2], b[3]);
                u.d[2] = pack2(b[4], b[5]); u.d[3] = pack2(b[6], b[7]);
                bt[t] = u.v;
            }
#pragma unroll
            for (int s = 0; s < 4; ++s)
#pragma unroll
                for (int t = 0; t < 2; ++t)
                    acc[s][t] = __builtin_amdgcn_mfma_f32_16x16x32_bf16(af[ks2][s], bt[t], acc[s][t], 0, 0, 0);
        }
    }

#pragma unroll
    for (int s = 0; s < 4; ++s)
#pragma unroll
        for (int r = 0; r < 4; ++r) {
            int row = s * 16 + q * 4 + r;
            int aid = s_aid[row];
            if (aid < 0) continue;
            int tok = (z == 32) ? aid : (aid >> 1);
            float w = s_w[row];
#pragma unroll
            for (int t = 0; t < 2; ++t) {
                int col = n0 + wid * 32 + t * 16 + lm;
                atomicAdd(&out[(size_t)tok * HID + col], w * acc[s][t][r]);
            }
        }
}

extern "C" void kernel_launch(void* const* d_in, const int* in_sizes, int n_in,
                              void* d_out, int out_size, void* d_ws, size_t ws_size,
                              hipStream_t stream)
{
    const float* x    = (const float*)d_in[0];
    const int*   tt   = (const int*)d_in[1];
    const float* rw_t = (const float*)d_in[2];
    const float* b_t  = (const float*)d_in[3];
    const float* gu_t = (const float*)d_in[4];
    const float* dn_t = (const float*)d_in[5];
    const float* rw_v = (const float*)d_in[6];
    const float* b_v  = (const float*)d_in[7];
    const float* gu_v = (const float*)d_in[8];
    const float* dn_v = (const float*)d_in[9];
    const float* sg   = (const float*)d_in[10];
    const float* su   = (const float*)d_in[11];
    const float* sd   = (const float*)d_in[12];
    float* out = (float*)d_out;
    float* out_logits = out + (size_t)TOK * HID;

    char* ws = (char*)d_ws;
    int*   counts = (int*)ws;                                   // 32 ints
    int*   lists  = (int*)(ws + 1024);                          // 32*1024 ints
    float* wlist  = (float*)(ws + 1024 + 32 * TOK * 4);         // 32*1024 floats
    unsigned short* hbuf = (unsigned short*)(ws + 1024 + 64 * TOK * 4);  // 2048x512 bf16 = 2 MB
    unsigned short* hsh  = hbuf + (size_t)2048 * 512;                    // 1024x1024 bf16 = 2 MB
    unsigned short* Xbf  = hsh + (size_t)1024 * 1024;                    // 1024x1024 bf16 = 2 MB

    hipLaunchKernelGGL(k_init, dim3(1024), dim3(256), 0, stream, out, counts);
    hipLaunchKernelGGL(k_router, dim3(TOK), dim3(64), 0, stream,
                       x, tt, rw_t, b_t, rw_v, b_v, out_logits, counts, lists, wlist, Xbf);
    hipLaunchKernelGGL(k_gu, dim3(16, 16, 33), dim3(256), 0, stream,
                       Xbf, gu_t, gu_v, sg, su, counts, lists, hbuf, hsh);
    hipLaunchKernelGGL(k_down, dim3(8, 16, 33), dim3(256), 0, stream,
                       hbuf, hsh, dn_t, dn_v, sd, counts, lists, wlist, out);
}

// Round 6
// 395.473 us; speedup vs baseline: 1.6584x; 1.6584x over previous
//
#include <hip/hip_runtime.h>
#include <math.h>

#define TOK  1024
#define HID  1024
#define NEXP 16

typedef __attribute__((ext_vector_type(8))) short bf16x8;
typedef __attribute__((ext_vector_type(4))) float f32x4;

// swizzled-weight region offsets (in bf16 elements)
#define SW_GUT 0u
#define SW_GUV 16777216u
#define SW_DNT 25165824u
#define SW_DNV 33554432u
#define SW_SG  37748736u
#define SW_SU  38797312u
#define SW_SD  39845888u
#define SW_ELEMS 40894464ull
#define WS_SMALL 6554624ull                    // counts/lists/wlist + hbuf+hsh+Xbf
#define WS_FAST (WS_SMALL + SW_ELEMS * 2ull)   // = 88343552

__device__ __forceinline__ unsigned pack2(float f0, float f1) {
    union { float f; unsigned u; } a, b; a.f = f0; b.f = f1;
    return __builtin_amdgcn_perm(b.u + 0x8000u, a.u + 0x8000u, 0x07060302u);
}
__device__ __forceinline__ unsigned short f2bf(float f) {
    union { float f; unsigned u; } v; v.f = f;
    return (unsigned short)((v.u + 0x8000u) >> 16);
}

// ---------------- init: zero counts + zero final-out region ----------------
__global__ void k_init(float* __restrict__ out, int* __restrict__ counts) {
    size_t i = (size_t)blockIdx.x * blockDim.x + threadIdx.x;   // 262144 float4
    ((float4*)out)[i] = make_float4(0.f, 0.f, 0.f, 0.f);
    if (blockIdx.x == 0 && threadIdx.x < 32) counts[threadIdx.x] = 0;
}

// ---------------- router: 1 wave per token (fp32 exact) + Xbf emission -----
__global__ __launch_bounds__(64)
void k_router(const float* __restrict__ x, const int* __restrict__ tt,
              const float* __restrict__ rw_t, const float* __restrict__ b_t,
              const float* __restrict__ rw_v, const float* __restrict__ b_v,
              float* __restrict__ out_logits,
              int* __restrict__ counts, int* __restrict__ lists,
              float* __restrict__ wlist, unsigned short* __restrict__ Xbf)
{
    const int t = blockIdx.x;
    const int lane = threadIdx.x;
    const bool vis = (tt[t] != 0);
    const float* rw   = vis ? rw_v : rw_t;
    const float* bias = vis ? b_v  : b_t;
    const float* xr = x + (size_t)t * HID;

#pragma unroll
    for (int jj = 0; jj < 2; ++jj) {
        int j0 = jj * 512 + lane * 8;
        float4 lo = *(const float4*)(xr + j0);
        float4 hi = *(const float4*)(xr + j0 + 4);
        union { bf16x8 v; unsigned d[4]; } u;
        u.d[0] = pack2(lo.x, lo.y); u.d[1] = pack2(lo.z, lo.w);
        u.d[2] = pack2(hi.x, hi.y); u.d[3] = pack2(hi.z, hi.w);
        *(bf16x8*)(Xbf + (size_t)t * HID + j0) = u.v;
    }

    float acc[NEXP];
#pragma unroll
    for (int e = 0; e < NEXP; ++e) acc[e] = 0.f;
    for (int j = 0; j < HID; j += 64) {
        const float xv = xr[j + lane];
#pragma unroll
        for (int e = 0; e < NEXP; ++e)
            acc[e] = fmaf(xv, rw[(size_t)e * HID + j + lane], acc[e]);
    }
#pragma unroll
    for (int e = 0; e < NEXP; ++e) {
        float v = acc[e];
#pragma unroll
        for (int off = 32; off; off >>= 1) v += __shfl_xor(v, off);
        acc[e] = v;
    }
    if (lane < NEXP) out_logits[(size_t)t * NEXP + lane] = acc[lane];

    if (lane == 0) {
        float mx = acc[0];
#pragma unroll
        for (int e = 1; e < NEXP; ++e) mx = fmaxf(mx, acc[e]);
        float p[NEXP], s = 0.f;
#pragma unroll
        for (int e = 0; e < NEXP; ++e) { p[e] = expf(acc[e] - mx); s += p[e]; }
        const float inv = 1.f / s;
#pragma unroll
        for (int e = 0; e < NEXP; ++e) p[e] *= inv;

        int s1 = 0; float v1 = p[0] + bias[0];
#pragma unroll
        for (int e = 1; e < NEXP; ++e) {
            float c = p[e] + bias[e];
            if (c > v1) { v1 = c; s1 = e; }
        }
        int s2 = -1; float v2 = -1e30f;
#pragma unroll
        for (int e = 0; e < NEXP; ++e) {
            if (e == s1) continue;
            float c = p[e] + bias[e];
            if (c > v2) { v2 = c; s2 = e; }
        }
        float w1 = p[s1], w2 = p[s2];
        float sw = fmaxf(w1 + w2, 1e-12f);
        w1 /= sw; w2 /= sw;

        const int base = vis ? NEXP : 0;
        int pos1 = atomicAdd(&counts[base + s1], 1);
        lists[(base + s1) * TOK + pos1] = t * 2 + 0;
        wlist[(base + s1) * TOK + pos1] = w1;
        int pos2 = atomicAdd(&counts[base + s2], 1);
        lists[(base + s2) * TOK + pos2] = t * 2 + 1;
        wlist[(base + s2) * TOK + pos2] = w2;
    }
}

// ---------------- weight convert/swizzle: fp32 [K][N] -> bf16 fragments ----
// Fragment tile (t=16 cols, c=32 k): 64 lanes x 8 bf16 contiguous at
// dst + ((t*(K/32)+c)*64 + lane)*8, lane=(q=k-quad)*16+(lm=col). One block
// handles one (matrix, c, 256-col panel): coalesced row loads -> LDS
// (stride 258: fragment reads are 2-way-bank = free) -> 16B frag stores.
__global__ __launch_bounds__(256)
void k_conv(const float* __restrict__ gut, const float* __restrict__ guv,
            const float* __restrict__ dnt, const float* __restrict__ dnv,
            const float* __restrict__ sg, const float* __restrict__ su,
            const float* __restrict__ sd, unsigned short* __restrict__ sw)
{
    __shared__ float ls[32 * 258];
    const int bid = blockIdx.x;
    const float* src; unsigned short* dst; int K, N, c, p;
    if (bid < 2048)      { int i = bid;        int e = i >> 7, r = i & 127; c = r >> 2; p = r & 3; K = 1024; N = 1024; src = gut + (size_t)e * 1048576; dst = sw + SW_GUT + (size_t)e * 1048576; }
    else if (bid < 3072) { int i = bid - 2048; int e = i >> 6, r = i & 63;  c = r >> 1; p = r & 1; K = 1024; N = 512;  src = guv + (size_t)e * 524288;  dst = sw + SW_GUV + (size_t)e * 524288; }
    else if (bid < 4096) { int i = bid - 3072; int e = i >> 6, r = i & 63;  c = r >> 2; p = r & 3; K = 512;  N = 1024; src = dnt + (size_t)e * 524288;  dst = sw + SW_DNT + (size_t)e * 524288; }
    else if (bid < 4608) { int i = bid - 4096; int e = i >> 5, r = i & 31;  c = r >> 2; p = r & 3; K = 256;  N = 1024; src = dnv + (size_t)e * 262144;  dst = sw + SW_DNV + (size_t)e * 262144; }
    else if (bid < 4736) { int i = bid - 4608; c = i >> 2; p = i & 3; K = 1024; N = 1024; src = sg; dst = sw + SW_SG; }
    else if (bid < 4864) { int i = bid - 4736; c = i >> 2; p = i & 3; K = 1024; N = 1024; src = su; dst = sw + SW_SU; }
    else                 { int i = bid - 4864; c = i >> 2; p = i & 3; K = 1024; N = 1024; src = sd; dst = sw + SW_SD; }

    const int k0 = c * 32, n0 = p * 256;
    const int tid = threadIdx.x;
#pragma unroll
    for (int i = 0; i < 8; ++i) {
        int u = tid + i * 256;                 // float4 index within 32x256
        int row = u >> 6, c4 = u & 63;
        float4 v = *(const float4*)(src + (size_t)(k0 + row) * N + n0 + c4 * 4);
        float* lp = &ls[row * 258 + c4 * 4];
        lp[0] = v.x; lp[1] = v.y; lp[2] = v.z; lp[3] = v.w;
    }
    __syncthreads();
    const int KC = K >> 5;
#pragma unroll
    for (int i = 0; i < 4; ++i) {
        int u = tid + i * 256;                 // 16 tiles x 64 lanes
        int tt = u >> 6, l = u & 63;
        int q = l >> 4, lm = l & 15;
        int col = tt * 16 + lm;
        unsigned d0 = pack2(ls[(q * 8 + 0) * 258 + col], ls[(q * 8 + 1) * 258 + col]);
        unsigned d1 = pack2(ls[(q * 8 + 2) * 258 + col], ls[(q * 8 + 3) * 258 + col]);
        unsigned d2 = pack2(ls[(q * 8 + 4) * 258 + col], ls[(q * 8 + 5) * 258 + col]);
        unsigned d3 = pack2(ls[(q * 8 + 6) * 258 + col], ls[(q * 8 + 7) * 258 + col]);
        size_t off = ((size_t)((p * 16 + tt) * KC + c) * 64 + l) * 8;
        *(uint4*)(dst + off) = make_uint4(d0, d1, d2, d3);
    }
}

// ---------------- gate+up GEMM + silu, streaming fragments (fast path) -----
// Block 64m x 64 i-cols; wave w owns i-cols [xI+w*16,+16): gate tile + up
// tile. Per 32-k chunk: 2 B-frag dwordx4 + 4 A-frag dwordx4 + 8 MFMA.
// No LDS tiles, no barriers, no packing.
__global__ __launch_bounds__(256)
void k_gu2(const unsigned short* __restrict__ Xbf, const unsigned short* __restrict__ sw,
           const int* __restrict__ counts, const int* __restrict__ lists,
           unsigned short* __restrict__ hbuf, unsigned short* __restrict__ hsh)
{
    const int z = blockIdx.z;
    int M, I, utile0;
    const unsigned short *gbase, *ubase;
    if (z == 32)      { M = TOK;       I = 1024; gbase = sw + SW_SG; ubase = sw + SW_SU; utile0 = 0; }
    else if (z < 16)  { M = counts[z]; I = 512;  gbase = ubase = sw + SW_GUT + (size_t)z * 1048576; utile0 = 32; }
    else              { M = counts[z]; I = 256;  gbase = ubase = sw + SW_GUV + (size_t)(z - 16) * 524288; utile0 = 16; }
    const int xI = blockIdx.x * 64, m0 = blockIdx.y * 64;
    if (xI >= I || m0 >= M) return;

    __shared__ int s_aid[64];
    const int tid = threadIdx.x;
    if (tid < 64) {
        int r = m0 + tid;
        s_aid[tid] = (z == 32) ? r : ((r < M) ? lists[z * TOK + r] : -1);
    }
    __syncthreads();

    const int w = tid >> 6, lane = tid & 63;
    const int lm = lane & 15, q = lane >> 4;

    const unsigned short* arow[4];
#pragma unroll
    for (int s = 0; s < 4; ++s) {
        int aid = s_aid[s * 16 + lm];
        int tr = (z == 32) ? aid : (aid < 0 ? 0 : (aid >> 1));
        arow[s] = Xbf + (size_t)tr * HID;
    }
    const int tg = (xI >> 4) + w;
    const int tu = utile0 + (xI >> 4) + w;
    const unsigned short* pg = gbase + (size_t)tg * 32 * 512 + lane * 8;
    const unsigned short* pu = ubase + (size_t)tu * 32 * 512 + lane * 8;
    const int ko = q * 8;

    f32x4 accG[4] = {}, accU[4] = {};
#pragma unroll 4
    for (int c = 0; c < 32; ++c) {
        bf16x8 bg = *(const bf16x8*)(pg + c * 512);
        bf16x8 bu = *(const bf16x8*)(pu + c * 512);
        const int kg = c * 32 + ko;
#pragma unroll
        for (int s = 0; s < 4; ++s) {
            bf16x8 af = *(const bf16x8*)(arow[s] + kg);
            accG[s] = __builtin_amdgcn_mfma_f32_16x16x32_bf16(af, bg, accG[s], 0, 0, 0);
            accU[s] = __builtin_amdgcn_mfma_f32_16x16x32_bf16(af, bu, accU[s], 0, 0, 0);
        }
    }

    const int i = xI + w * 16 + lm;
#pragma unroll
    for (int s = 0; s < 4; ++s)
#pragma unroll
        for (int r = 0; r < 4; ++r) {
            int row = s * 16 + q * 4 + r;
            int aid = s_aid[row];
            if (aid < 0) continue;
            float g = accG[s][r], uu = accU[s][r];
            float h = g / (1.f + __expf(-g)) * uu;
            if (z == 32) hsh[(size_t)aid * 1024 + i] = f2bf(h);
            else         hbuf[(size_t)aid * 512 + i] = f2bf(h);
        }
}

// ---------------- down GEMM, streaming fragments (fast path) ---------------
__global__ __launch_bounds__(256)
void k_down2(const unsigned short* __restrict__ hbuf, const unsigned short* __restrict__ hsh,
             const unsigned short* __restrict__ sw,
             const int* __restrict__ counts, const int* __restrict__ lists,
             const float* __restrict__ wlist, float* __restrict__ out)
{
    const int z = blockIdx.z;
    int M, K;
    const unsigned short* base;
    if (z == 32)     { M = TOK;       K = 1024; base = sw + SW_SD; }
    else if (z < 16) { M = counts[z]; K = 512;  base = sw + SW_DNT + (size_t)z * 524288; }
    else             { M = counts[z]; K = 256;  base = sw + SW_DNV + (size_t)(z - 16) * 262144; }
    const int n0 = blockIdx.x * 64, m0 = blockIdx.y * 64;
    if (m0 >= M) return;

    __shared__ int s_aid[64];
    __shared__ float s_w[64];
    const int tid = threadIdx.x;
    if (tid < 64) {
        int r = m0 + tid;
        if (z == 32)    { s_aid[tid] = r; s_w[tid] = 1.f; }
        else if (r < M) { s_aid[tid] = lists[z * TOK + r]; s_w[tid] = wlist[z * TOK + r]; }
        else            { s_aid[tid] = -1; s_w[tid] = 0.f; }
    }
    __syncthreads();

    const int w = tid >> 6, lane = tid & 63;
    const int lm = lane & 15, q = lane >> 4;

    const unsigned short* hrow[4];
#pragma unroll
    for (int s = 0; s < 4; ++s) {
        int aid = s_aid[s * 16 + lm];
        hrow[s] = (z == 32) ? (hsh + (size_t)aid * 1024)
                            : (hbuf + (size_t)(aid < 0 ? 0 : aid) * 512);
    }
    const int KC = K >> 5;
    const int t = (n0 >> 4) + w;
    const unsigned short* pb = base + (size_t)t * KC * 512 + lane * 8;
    const int ko = q * 8;

    f32x4 acc[4] = {};
#pragma unroll 4
    for (int c = 0; c < KC; ++c) {
        bf16x8 bt = *(const bf16x8*)(pb + c * 512);
        const int kg = c * 32 + ko;
#pragma unroll
        for (int s = 0; s < 4; ++s) {
            bf16x8 af = *(const bf16x8*)(hrow[s] + kg);
            acc[s] = __builtin_amdgcn_mfma_f32_16x16x32_bf16(af, bt, acc[s], 0, 0, 0);
        }
    }

    const int col = n0 + w * 16 + lm;
#pragma unroll
    for (int s = 0; s < 4; ++s)
#pragma unroll
        for (int r = 0; r < 4; ++r) {
            int row = s * 16 + q * 4 + r;
            int aid = s_aid[row];
            if (aid < 0) continue;
            int tok = (z == 32) ? aid : (aid >> 1);
            atomicAdd(&out[(size_t)tok * HID + col], s_w[row] * acc[s][r]);
        }
}

// ================= fallback path (small ws): r5 kernels, uncapped bounds ===
__global__ __launch_bounds__(256)
void k_gu_fb(const unsigned short* __restrict__ Xbf,
             const float* __restrict__ gut, const float* __restrict__ guv,
             const float* __restrict__ sg, const float* __restrict__ su,
             const int* __restrict__ counts, const int* __restrict__ lists,
             unsigned short* __restrict__ hbuf, unsigned short* __restrict__ hsh)
{
    const int z = blockIdx.z;
    int M, I, str;
    const float *Wg, *Wu;
    if (z == 32) { M = TOK; I = 1024; str = 1024; Wg = sg; Wu = su; }
    else {
        M = counts[z];
        const int mod = z >> 4, e = z & 15;
        I = mod ? 256 : 512; str = 2 * I;
        const float* base = mod ? (guv + (size_t)e * HID * 512)
                                : (gut + (size_t)e * HID * 1024);
        Wg = base; Wu = base + I;
    }
    const int xI = blockIdx.x * 64;
    const int m0 = blockIdx.y * 64;
    if (xI >= I || m0 >= M) return;

    __shared__ float bs[8192];
    __shared__ int s_aid[64];
    const int tid = threadIdx.x;
    const int wid = tid >> 6, lane = tid & 63;
    const int lm = lane & 15, q = lane >> 4;

    if (tid < 64) {
        int r = m0 + tid;
        s_aid[tid] = (z == 32) ? r : ((r < M) ? lists[z * TOK + r] : -1);
    }
    __syncthreads();

    const unsigned short* arow[4];
#pragma unroll
    for (int s = 0; s < 4; ++s) {
        int aid = s_aid[s * 16 + lm];
        int tr = (z == 32) ? aid : (aid < 0 ? 0 : (aid >> 1));
        arow[s] = Xbf + (size_t)tr * HID;
    }
    int urow[8], uc4[8], scell[8];
#pragma unroll
    for (int r = 0; r < 8; ++r) {
        int u = r * 256 + tid;
        int k = u >> 5;
        urow[r] = k; uc4[r] = u & 31;
        scell[r] = k * 32 + ((u & 31) ^ (((k >> 3) & 1) << 2));
    }
    int fidx[2];
#pragma unroll
    for (int reg = 0; reg < 2; ++reg) {
        int c = reg * 64 + wid * 16 + lm;
        fidx[reg] = (q * 8) * 128 + (((c >> 2) ^ ((q & 1) << 2)) * 4 + (c & 3));
    }
    float4 R[8];
#pragma unroll
    for (int r = 0; r < 8; ++r) {
        int c4 = uc4[r];
        const float* gp = (c4 < 16) ? (Wg + (size_t)urow[r] * str + xI + c4 * 4)
                                    : (Wu + (size_t)urow[r] * str + xI + (c4 - 16) * 4);
        R[r] = *(const float4*)gp;
    }
    f32x4 accG[4] = {}, accU[4] = {};
    for (int kc = 0; kc < 16; ++kc) {
        if (kc) __syncthreads();
#pragma unroll
        for (int r = 0; r < 8; ++r)
            *(float4*)&bs[scell[r] * 4] = R[r];
        __syncthreads();
        bf16x8 af[2][4];
        const int kg = kc * 64 + q * 8;
#pragma unroll
        for (int s = 0; s < 4; ++s) {
            af[0][s] = *(const bf16x8*)(arow[s] + kg);
            af[1][s] = *(const bf16x8*)(arow[s] + kg + 32);
        }
        if (kc + 1 < 16) {
            const int k0 = (kc + 1) * 64;
#pragma unroll
            for (int r = 0; r < 8; ++r) {
                int c4 = uc4[r];
                const float* gp = (c4 < 16) ? (Wg + (size_t)(k0 + urow[r]) * str + xI + c4 * 4)
                                            : (Wu + (size_t)(k0 + urow[r]) * str + xI + (c4 - 16) * 4);
                R[r] = *(const float4*)gp;
            }
        }
#pragma unroll
        for (int ks2 = 0; ks2 < 2; ++ks2) {
            const int ks = ks2 * 32;
            bf16x8 bg, bu;
            {
                float b[8];
#pragma unroll
                for (int j = 0; j < 8; ++j) b[j] = bs[fidx[0] + (ks + j) * 128];
                union { bf16x8 v; unsigned d[4]; } u;
                u.d[0] = pack2(b[0], b[1]); u.d[1] = pack2(b[2], b[3]);
                u.d[2] = pack2(b[4], b[5]); u.d[3] = pack2(b[6], b[7]);
                bg = u.v;
            }
            {
                float b[8];
#pragma unroll
                for (int j = 0; j < 8; ++j) b[j] = bs[fidx[1] + (ks + j) * 128];
                union { bf16x8 v; unsigned d[4]; } u;
                u.d[0] = pack2(b[0], b[1]); u.d[1] = pack2(b[2], b[3]);
                u.d[2] = pack2(b[4], b[5]); u.d[3] = pack2(b[6], b[7]);
                bu = u.v;
            }
#pragma unroll
            for (int s = 0; s < 4; ++s) {
                accG[s] = __builtin_amdgcn_mfma_f32_16x16x32_bf16(af[ks2][s], bg, accG[s], 0, 0, 0);
                accU[s] = __builtin_amdgcn_mfma_f32_16x16x32_bf16(af[ks2][s], bu, accU[s], 0, 0, 0);
            }
        }
    }
    const int i = xI + wid * 16 + lm;
#pragma unroll
    for (int s = 0; s < 4; ++s)
#pragma unroll
        for (int r = 0; r < 4; ++r) {
            int row = s * 16 + q * 4 + r;
            int aid = s_aid[row];
            if (aid < 0) continue;
            float g = accG[s][r], uu = accU[s][r];
            float h = g / (1.f + __expf(-g)) * uu;
            if (z == 32) hsh[(size_t)aid * 1024 + i] = f2bf(h);
            else         hbuf[(size_t)aid * 512 + i] = f2bf(h);
        }
}

__global__ __launch_bounds__(256)
void k_down_fb(const unsigned short* __restrict__ hbuf, const unsigned short* __restrict__ hsh,
               const float* __restrict__ dnt, const float* __restrict__ dnv,
               const float* __restrict__ sd,
               const int* __restrict__ counts, const int* __restrict__ lists,
               const float* __restrict__ wlist, float* __restrict__ out)
{
    const int z = blockIdx.z;
    int M, K;
    const float* W;
    if (z == 32) { M = TOK; K = 1024; W = sd; }
    else {
        M = counts[z];
        const int mod = z >> 4, e = z & 15;
        K = mod ? 256 : 512;
        W = mod ? (dnv + (size_t)e * 256 * 1024) : (dnt + (size_t)e * 512 * 1024);
    }
    const int n0 = blockIdx.x * 128;
    const int m0 = blockIdx.y * 64;
    if (m0 >= M) return;

    __shared__ float bs[8192];
    __shared__ int s_aid[64];
    __shared__ float s_w[64];
    const int tid = threadIdx.x;
    const int wid = tid >> 6, lane = tid & 63;
    const int lm = lane & 15, q = lane >> 4;

    if (tid < 64) {
        int r = m0 + tid;
        if (z == 32)    { s_aid[tid] = r; s_w[tid] = 1.f; }
        else if (r < M) { s_aid[tid] = lists[z * TOK + r]; s_w[tid] = wlist[z * TOK + r]; }
        else            { s_aid[tid] = -1; s_w[tid] = 0.f; }
    }
    __syncthreads();

    const unsigned short* hrow[4];
#pragma unroll
    for (int s = 0; s < 4; ++s) {
        int aid = s_aid[s * 16 + lm];
        hrow[s] = (z == 32) ? (hsh + (size_t)aid * 1024)
                            : (hbuf + (size_t)(aid < 0 ? 0 : aid) * 512);
    }
    int urow[8], uc4[8], scell[8];
#pragma unroll
    for (int r = 0; r < 8; ++r) {
        int u = r * 256 + tid;
        int k = u >> 5;
        urow[r] = k; uc4[r] = u & 31;
        scell[r] = k * 32 + ((u & 31) ^ (((k >> 3) & 1) << 2));
    }
    int fidx[2];
#pragma unroll
    for (int t = 0; t < 2; ++t) {
        int c = wid * 32 + t * 16 + lm;
        fidx[t] = (q * 8) * 128 + (((c >> 2) ^ ((q & 1) << 2)) * 4 + (c & 3));
    }
    float4 R[8];
#pragma unroll
    for (int r = 0; r < 8; ++r)
        R[r] = *(const float4*)(W + (size_t)urow[r] * 1024 + n0 + uc4[r] * 4);

    f32x4 acc[4][2] = {};
    const int NC = K >> 6;
    for (int kc = 0; kc < NC; ++kc) {
        if (kc) __syncthreads();
#pragma unroll
        for (int r = 0; r < 8; ++r)
            *(float4*)&bs[scell[r] * 4] = R[r];
        __syncthreads();
        bf16x8 af[2][4];
        const int kg = kc * 64 + q * 8;
#pragma unroll
        for (int s = 0; s < 4; ++s) {
            af[0][s] = *(const bf16x8*)(hrow[s] + kg);
            af[1][s] = *(const bf16x8*)(hrow[s] + kg + 32);
        }
        if (kc + 1 < NC) {
            const int k0 = (kc + 1) * 64;
#pragma unroll
            for (int r = 0; r < 8; ++r)
                R[r] = *(const float4*)(W + (size_t)(k0 + urow[r]) * 1024 + n0 + uc4[r] * 4);
        }
#pragma unroll
        for (int ks2 = 0; ks2 < 2; ++ks2) {
            const int ks = ks2 * 32;
            bf16x8 bt[2];
#pragma unroll
            for (int t = 0; t < 2; ++t) {
                float b[8];
#pragma unroll
                for (int j = 0; j < 8; ++j) b[j] = bs[fidx[t] + (ks + j) * 128];
                union { bf16x8 v; unsigned d[4]; } u;
                u.d[0] = pack2(b[0], b[1]); u.d[1] = pack2(b[2], b[3]);
                u.d[2] = pack2(b[4], b[5]); u.d[3] = pack2(b[6], b[7]);
                bt[t] = u.v;
            }
#pragma unroll
            for (int s = 0; s < 4; ++s)
#pragma unroll
                for (int t = 0; t < 2; ++t)
                    acc[s][t] = __builtin_amdgcn_mfma_f32_16x16x32_bf16(af[ks2][s], bt[t], acc[s][t], 0, 0, 0);
        }
    }
#pragma unroll
    for (int s = 0; s < 4; ++s)
#pragma unroll
        for (int r = 0; r < 4; ++r) {
            int row = s * 16 + q * 4 + r;
            int aid = s_aid[row];
            if (aid < 0) continue;
            int tok = (z == 32) ? aid : (aid >> 1);
            float w = s_w[row];
#pragma unroll
            for (int t = 0; t < 2; ++t) {
                int col = n0 + wid * 32 + t * 16 + lm;
                atomicAdd(&out[(size_t)tok * HID + col], w * acc[s][t][r]);
            }
        }
}

extern "C" void kernel_launch(void* const* d_in, const int* in_sizes, int n_in,
                              void* d_out, int out_size, void* d_ws, size_t ws_size,
                              hipStream_t stream)
{
    const float* x    = (const float*)d_in[0];
    const int*   tt   = (const int*)d_in[1];
    const float* rw_t = (const float*)d_in[2];
    const float* b_t  = (const float*)d_in[3];
    const float* gu_t = (const float*)d_in[4];
    const float* dn_t = (const float*)d_in[5];
    const float* rw_v = (const float*)d_in[6];
    const float* b_v  = (const float*)d_in[7];
    const float* gu_v = (const float*)d_in[8];
    const float* dn_v = (const float*)d_in[9];
    const float* sg   = (const float*)d_in[10];
    const float* su   = (const float*)d_in[11];
    const float* sd   = (const float*)d_in[12];
    float* out = (float*)d_out;
    float* out_logits = out + (size_t)TOK * HID;

    char* ws = (char*)d_ws;
    int*   counts = (int*)ws;                                   // 32 ints
    int*   lists  = (int*)(ws + 1024);                          // 32*1024 ints
    float* wlist  = (float*)(ws + 1024 + 32 * TOK * 4);         // 32*1024 floats
    unsigned short* hbuf = (unsigned short*)(ws + 1024 + 64 * TOK * 4);  // 2048x512 bf16
    unsigned short* hsh  = hbuf + (size_t)2048 * 512;                    // 1024x1024 bf16
    unsigned short* Xbf  = hsh + (size_t)1024 * 1024;                    // 1024x1024 bf16
    unsigned short* swz  = Xbf + (size_t)1024 * 1024;                    // 78 MB swizzled weights

    hipLaunchKernelGGL(k_init, dim3(1024), dim3(256), 0, stream, out, counts);
    hipLaunchKernelGGL(k_router, dim3(TOK), dim3(64), 0, stream,
                       x, tt, rw_t, b_t, rw_v, b_v, out_logits, counts, lists, wlist, Xbf);
    if (ws_size >= WS_FAST) {
        hipLaunchKernelGGL(k_conv, dim3(4992), dim3(256), 0, stream,
                           gu_t, gu_v, dn_t, dn_v, sg, su, sd, swz);
        hipLaunchKernelGGL(k_gu2, dim3(16, 16, 33), dim3(256), 0, stream,
                           Xbf, swz, counts, lists, hbuf, hsh);
        hipLaunchKernelGGL(k_down2, dim3(16, 16, 33), dim3(256), 0, stream,
                           hbuf, hsh, swz, counts, lists, wlist, out);
    } else {
        hipLaunchKernelGGL(k_gu_fb, dim3(16, 16, 33), dim3(256), 0, stream,
                           Xbf, gu_t, gu_v, sg, su, counts, lists, hbuf, hsh);
        hipLaunchKernelGGL(k_down_fb, dim3(8, 16, 33), dim3(256), 0, stream,
                           hbuf, hsh, dn_t, dn_v, sd, counts, lists, wlist, out);
    }
}